// Round 7
// baseline (125.385 us; speedup 1.0000x reference)
//
#include <hip/hip_runtime.h>

#define B_N 16
#define C_N 3
#define H_N 512
#define W_N 512
#define PLANES (B_N * C_N)            // 48
#define ROWS_PER_BLOCK 32
#define CHUNKS (H_N / ROWS_PER_BLOCK) // 16
#define NBLK (PLANES * CHUNKS)        // 768
#define STATS3 (W_N * 3)              // 1536
#define K2_BLOCKS (PLANES * 2)        // 96 (2 blocks per plane, 256 cols each)
#define SCALE (-1.0f / 8192.0f)       // -1/(B*H) == -1/(B*W), weights all 1
#define EPS_F 1e-12f

// native clang vector type: __builtin_nontemporal_load requires it
// (HIP_vector_type float4 is a struct and is rejected).
typedef float vfloat4 __attribute__((ext_vector_type(4)));

// K1: single streaming pass, reads x and ref exactly once.
// Round-7 = round-6 retry (compile fix only). Rationale: K1's effective
// read rate is pinned at ~2.3-2.8 TB/s across occupancy 10-50%, VGPR
// 40-140, with/without in-loop shuffles — consistent with a per-CU
// outstanding-read-miss cap (≈4 KB in flight / 375 ns ≈ 11 GB/s/CU ≈
// 2.8 TB/s device-wide). Single change vs r4 (best, 120.5 µs):
// NONTEMPORAL loads for x/ref — the stream is read-once (the 256 MB poison
// fill sweeps L3 each iteration), nt avoids L1/L2 allocation and stops
// evicting dirty poison lines (~45 MB writeback seen during K1 in r2).
__global__ __launch_bounds__(256) void spl_main_kernel(
    const float* __restrict__ x, const float* __restrict__ r,
    float* __restrict__ colpart, float* __restrict__ rowpart,
    unsigned int* __restrict__ counter) {
    if (blockIdx.x == 0 && threadIdx.x == 0)
        __hip_atomic_store(counter, 0u, __ATOMIC_RELAXED, __HIP_MEMORY_SCOPE_AGENT);

    const int p     = blockIdx.x / CHUNKS;
    const int chunk = blockIdx.x % CHUNKS;
    const int wave  = threadIdx.x >> 6;
    const int lane  = threadIdx.x & 63;

    const float* xp = x + (size_t)p * (H_N * W_N);
    const float* rp = r + (size_t)p * (H_N * W_N);

    float cxx[8] = {0, 0, 0, 0, 0, 0, 0, 0};
    float crr[8] = {0, 0, 0, 0, 0, 0, 0, 0};
    float cxr[8] = {0, 0, 0, 0, 0, 0, 0, 0};
    float rowacc = 0.0f;  // valid on lane 0

    const int r0 = chunk * ROWS_PER_BLOCK;
    for (int j = 0; j < ROWS_PER_BLOCK / 4; ++j) {
        const int row = r0 + wave + 4 * j;
        const vfloat4* xr4 = (const vfloat4*)(xp + (size_t)row * W_N);
        const vfloat4* rr4 = (const vfloat4*)(rp + (size_t)row * W_N);
        const vfloat4 xa = __builtin_nontemporal_load(&xr4[lane]);
        const vfloat4 xb = __builtin_nontemporal_load(&xr4[lane + 64]);
        const vfloat4 ra = __builtin_nontemporal_load(&rr4[lane]);
        const vfloat4 rb = __builtin_nontemporal_load(&rr4[lane + 64]);

        cxx[0] += xa.x * xa.x; cxx[1] += xa.y * xa.y; cxx[2] += xa.z * xa.z; cxx[3] += xa.w * xa.w;
        cxx[4] += xb.x * xb.x; cxx[5] += xb.y * xb.y; cxx[6] += xb.z * xb.z; cxx[7] += xb.w * xb.w;
        crr[0] += ra.x * ra.x; crr[1] += ra.y * ra.y; crr[2] += ra.z * ra.z; crr[3] += ra.w * ra.w;
        crr[4] += rb.x * rb.x; crr[5] += rb.y * rb.y; crr[6] += rb.z * rb.z; crr[7] += rb.w * rb.w;
        cxr[0] += xa.x * ra.x; cxr[1] += xa.y * ra.y; cxr[2] += xa.z * ra.z; cxr[3] += xa.w * ra.w;
        cxr[4] += xb.x * rb.x; cxr[5] += xb.y * rb.y; cxr[6] += xb.z * rb.z; cxr[7] += xb.w * rb.w;

        float sxx = xa.x * xa.x + xa.y * xa.y + xa.z * xa.z + xa.w * xa.w
                  + xb.x * xb.x + xb.y * xb.y + xb.z * xb.z + xb.w * xb.w;
        float srr = ra.x * ra.x + ra.y * ra.y + ra.z * ra.z + ra.w * ra.w
                  + rb.x * rb.x + rb.y * rb.y + rb.z * rb.z + rb.w * rb.w;
        float sxr = xa.x * ra.x + xa.y * ra.y + xa.z * ra.z + xa.w * ra.w
                  + xb.x * rb.x + xb.y * rb.y + xb.z * rb.z + xb.w * rb.w;
        #pragma unroll
        for (int m = 32; m > 0; m >>= 1) {
            sxx += __shfl_down(sxx, m, 64);
            srr += __shfl_down(srr, m, 64);
            sxr += __shfl_down(sxr, m, 64);
        }
        if (lane == 0) {
            const float nx = fmaxf(sqrtf(sxx), EPS_F);
            const float nr = fmaxf(sqrtf(srr), EPS_F);
            rowacc += sxr / (nx * nr);
        }
    }

    // combine column partials across the block's 4 waves via LDS
    __shared__ float smem[4][STATS3];  // 24 KiB
    #pragma unroll
    for (int k = 0; k < 4; ++k) {
        const int c0 = 4 * lane + k;
        const int c1 = c0 + 256;
        smem[wave][c0 * 3 + 0] = cxx[k];
        smem[wave][c0 * 3 + 1] = crr[k];
        smem[wave][c0 * 3 + 2] = cxr[k];
        smem[wave][c1 * 3 + 0] = cxx[4 + k];
        smem[wave][c1 * 3 + 1] = crr[4 + k];
        smem[wave][c1 * 3 + 2] = cxr[4 + k];
    }
    __shared__ float rowsums[4];
    if (lane == 0) rowsums[wave] = rowacc;
    __syncthreads();

    float* cp = colpart + (size_t)blockIdx.x * STATS3;
    #pragma unroll
    for (int k = 0; k < 6; ++k) {
        const int e = threadIdx.x + 256 * k;
        cp[e] = smem[0][e] + smem[1][e] + smem[2][e] + smem[3][e];
    }
    if (threadIdx.x == 0)
        rowpart[blockIdx.x] = rowsums[0] + rowsums[1] + rowsums[2] + rowsums[3];
}

// K2 (fused final): 96 blocks, 2 per plane (256 columns each). Reduces the
// 16 chunk partials, forms 256 column cosine terms, half 0 adds the 16 row
// partial sums, publishes planepart[b] device-scope; the LAST block folds
// the 96 partials and writes the output (saves the K3 launch).
__global__ __launch_bounds__(256) void spl_reduce_kernel(
    const float* __restrict__ colpart, const float* __restrict__ rowpart,
    float* __restrict__ planepart, unsigned int* __restrict__ counter,
    float* __restrict__ out) {
    const int p    = blockIdx.x >> 1;
    const int half = blockIdx.x & 1;

    float acc0 = 0.0f, acc1 = 0.0f, acc2 = 0.0f;
    const float* base = colpart + (size_t)p * CHUNKS * STATS3 + half * 768;
    #pragma unroll 4
    for (int c = 0; c < CHUNKS; ++c) {
        const float* bc = base + c * STATS3;
        acc0 += bc[threadIdx.x];
        acc1 += bc[threadIdx.x + 256];
        acc2 += bc[threadIdx.x + 512];
    }
    __shared__ float sums[768];
    sums[threadIdx.x]       = acc0;
    sums[threadIdx.x + 256] = acc1;
    sums[threadIdx.x + 512] = acc2;
    __syncthreads();

    // one column per thread; stride-3 -> max 2 lanes/bank, free on CDNA4.
    const float sxx = sums[3 * threadIdx.x + 0];
    const float srr = sums[3 * threadIdx.x + 1];
    const float sxr = sums[3 * threadIdx.x + 2];
    float term = sxr / (fmaxf(sqrtf(sxx), EPS_F) * fmaxf(sqrtf(srr), EPS_F));
    if (half == 0 && threadIdx.x < CHUNKS)
        term += rowpart[p * CHUNKS + threadIdx.x];

    #pragma unroll
    for (int m = 32; m > 0; m >>= 1) term += __shfl_down(term, m, 64);
    __shared__ float ws4[4];
    if ((threadIdx.x & 63) == 0) ws4[threadIdx.x >> 6] = term;
    __syncthreads();

    __shared__ bool last;
    if (threadIdx.x == 0) {
        const float total = ws4[0] + ws4[1] + ws4[2] + ws4[3];
        __hip_atomic_store(&planepart[blockIdx.x], total, __ATOMIC_RELEASE,
                           __HIP_MEMORY_SCOPE_AGENT);
        const unsigned int prev = __hip_atomic_fetch_add(
            counter, 1u, __ATOMIC_ACQ_REL, __HIP_MEMORY_SCOPE_AGENT);
        last = (prev == K2_BLOCKS - 1);
    }
    __syncthreads();

    if (last && threadIdx.x < 64) {
        const int t = threadIdx.x;
        float v = __hip_atomic_load(&planepart[t], __ATOMIC_ACQUIRE,
                                    __HIP_MEMORY_SCOPE_AGENT);
        if (t < K2_BLOCKS - 64)
            v += __hip_atomic_load(&planepart[t + 64], __ATOMIC_ACQUIRE,
                                   __HIP_MEMORY_SCOPE_AGENT);
        #pragma unroll
        for (int m = 32; m > 0; m >>= 1) v += __shfl_down(v, m, 64);
        if (t == 0) out[0] = SCALE * v;
    }
}

extern "C" void kernel_launch(void* const* d_in, const int* in_sizes, int n_in,
                              void* d_out, int out_size, void* d_ws, size_t ws_size,
                              hipStream_t stream) {
    const float* x   = (const float*)d_in[0];
    const float* ref = (const float*)d_in[1];
    float* out = (float*)d_out;

    float* colpart   = (float*)d_ws;                      // 768*1536 floats
    float* rowpart   = colpart + (size_t)NBLK * STATS3;   // 768 floats
    float* planepart = rowpart + NBLK;                    // 96 floats
    unsigned int* counter = (unsigned int*)(planepart + K2_BLOCKS);  // 1 uint

    spl_main_kernel<<<NBLK, 256, 0, stream>>>(x, ref, colpart, rowpart, counter);
    spl_reduce_kernel<<<K2_BLOCKS, 256, 0, stream>>>(colpart, rowpart, planepart,
                                                     counter, out);
}

// Round 8
// 120.212 us; speedup vs baseline: 1.0430x; 1.0430x over previous
//
#include <hip/hip_runtime.h>

#define B_N 16
#define C_N 3
#define H_N 512
#define W_N 512
#define PLANES (B_N * C_N)            // 48
#define ROWS_PER_BLOCK 32
#define CHUNKS (H_N / ROWS_PER_BLOCK) // 16
#define NBLK (PLANES * CHUNKS)        // 768
#define STATS3 (W_N * 3)              // 1536
#define K2_BLOCKS (PLANES * 2)        // 96 (2 blocks per plane, 256 cols each)
#define SCALE (-1.0f / 8192.0f)       // -1/(B*H) == -1/(B*W), weights all 1
#define EPS_F 1e-12f

// K1: single streaming pass, reads x and ref exactly once.
// FINAL (r8 = r4 revert, best measured 120.5 µs total). Ladder evidence:
//  - r1 (full unroll, 140 VGPR): 44-50 µs   - r2 (occ 48%, 40 VGPR): 45 µs
//  - r5 (zero cross-lane in loop): ~36 µs   - r7 (nontemporal): ~+5 µs
//  - this structure: ~36 µs.
// Effective read rate is pinned at ~2.8 TB/s across ALL variants —
// consistent with the per-CU outstanding-read-miss cap (~4 KB in flight /
// ~375 ns HBM latency × 256 CU). Occupancy, ILP, shuffle placement and
// cache hints are all measured-invariant. Remaining total = ~82 µs harness
// poison fills + ~36 µs K1 at the read cap + ~4 µs K2/gaps.
__global__ __launch_bounds__(256) void spl_main_kernel(
    const float* __restrict__ x, const float* __restrict__ r,
    float* __restrict__ colpart, float* __restrict__ rowpart,
    unsigned int* __restrict__ counter) {
    if (blockIdx.x == 0 && threadIdx.x == 0)
        __hip_atomic_store(counter, 0u, __ATOMIC_RELAXED, __HIP_MEMORY_SCOPE_AGENT);

    const int p     = blockIdx.x / CHUNKS;
    const int chunk = blockIdx.x % CHUNKS;
    const int wave  = threadIdx.x >> 6;
    const int lane  = threadIdx.x & 63;

    const float* xp = x + (size_t)p * (H_N * W_N);
    const float* rp = r + (size_t)p * (H_N * W_N);

    float cxx[8] = {0, 0, 0, 0, 0, 0, 0, 0};
    float crr[8] = {0, 0, 0, 0, 0, 0, 0, 0};
    float cxr[8] = {0, 0, 0, 0, 0, 0, 0, 0};
    float rowacc = 0.0f;  // valid on lane 0

    const int r0 = chunk * ROWS_PER_BLOCK;
    for (int j = 0; j < ROWS_PER_BLOCK / 4; ++j) {
        const int row = r0 + wave + 4 * j;
        const float4* xr4 = (const float4*)(xp + (size_t)row * W_N);
        const float4* rr4 = (const float4*)(rp + (size_t)row * W_N);
        const float4 xa = xr4[lane];
        const float4 xb = xr4[lane + 64];
        const float4 ra = rr4[lane];
        const float4 rb = rr4[lane + 64];

        cxx[0] += xa.x * xa.x; cxx[1] += xa.y * xa.y; cxx[2] += xa.z * xa.z; cxx[3] += xa.w * xa.w;
        cxx[4] += xb.x * xb.x; cxx[5] += xb.y * xb.y; cxx[6] += xb.z * xb.z; cxx[7] += xb.w * xb.w;
        crr[0] += ra.x * ra.x; crr[1] += ra.y * ra.y; crr[2] += ra.z * ra.z; crr[3] += ra.w * ra.w;
        crr[4] += rb.x * rb.x; crr[5] += rb.y * rb.y; crr[6] += rb.z * rb.z; crr[7] += rb.w * rb.w;
        cxr[0] += xa.x * ra.x; cxr[1] += xa.y * ra.y; cxr[2] += xa.z * ra.z; cxr[3] += xa.w * ra.w;
        cxr[4] += xb.x * rb.x; cxr[5] += xb.y * rb.y; cxr[6] += xb.z * rb.z; cxr[7] += xb.w * rb.w;

        float sxx = xa.x * xa.x + xa.y * xa.y + xa.z * xa.z + xa.w * xa.w
                  + xb.x * xb.x + xb.y * xb.y + xb.z * xb.z + xb.w * xb.w;
        float srr = ra.x * ra.x + ra.y * ra.y + ra.z * ra.z + ra.w * ra.w
                  + rb.x * rb.x + rb.y * rb.y + rb.z * rb.z + rb.w * rb.w;
        float sxr = xa.x * ra.x + xa.y * ra.y + xa.z * ra.z + xa.w * ra.w
                  + xb.x * rb.x + xb.y * rb.y + xb.z * rb.z + xb.w * rb.w;
        #pragma unroll
        for (int m = 32; m > 0; m >>= 1) {
            sxx += __shfl_down(sxx, m, 64);
            srr += __shfl_down(srr, m, 64);
            sxr += __shfl_down(sxr, m, 64);
        }
        if (lane == 0) {
            const float nx = fmaxf(sqrtf(sxx), EPS_F);
            const float nr = fmaxf(sqrtf(srr), EPS_F);
            rowacc += sxr / (nx * nr);
        }
    }

    // combine column partials across the block's 4 waves via LDS
    __shared__ float smem[4][STATS3];  // 24 KiB
    #pragma unroll
    for (int k = 0; k < 4; ++k) {
        const int c0 = 4 * lane + k;
        const int c1 = c0 + 256;
        smem[wave][c0 * 3 + 0] = cxx[k];
        smem[wave][c0 * 3 + 1] = crr[k];
        smem[wave][c0 * 3 + 2] = cxr[k];
        smem[wave][c1 * 3 + 0] = cxx[4 + k];
        smem[wave][c1 * 3 + 1] = crr[4 + k];
        smem[wave][c1 * 3 + 2] = cxr[4 + k];
    }
    __shared__ float rowsums[4];
    if (lane == 0) rowsums[wave] = rowacc;
    __syncthreads();

    float* cp = colpart + (size_t)blockIdx.x * STATS3;
    #pragma unroll
    for (int k = 0; k < 6; ++k) {
        const int e = threadIdx.x + 256 * k;
        cp[e] = smem[0][e] + smem[1][e] + smem[2][e] + smem[3][e];
    }
    if (threadIdx.x == 0)
        rowpart[blockIdx.x] = rowsums[0] + rowsums[1] + rowsums[2] + rowsums[3];
}

// K2 (fused final): 96 blocks, 2 per plane (256 columns each). Reduces the
// 16 chunk partials, forms 256 column cosine terms, half 0 adds the 16 row
// partial sums, publishes planepart[b] device-scope; the LAST block folds
// the 96 partials and writes the output (saves the K3 launch).
__global__ __launch_bounds__(256) void spl_reduce_kernel(
    const float* __restrict__ colpart, const float* __restrict__ rowpart,
    float* __restrict__ planepart, unsigned int* __restrict__ counter,
    float* __restrict__ out) {
    const int p    = blockIdx.x >> 1;
    const int half = blockIdx.x & 1;

    float acc0 = 0.0f, acc1 = 0.0f, acc2 = 0.0f;
    const float* base = colpart + (size_t)p * CHUNKS * STATS3 + half * 768;
    #pragma unroll 4
    for (int c = 0; c < CHUNKS; ++c) {
        const float* bc = base + c * STATS3;
        acc0 += bc[threadIdx.x];
        acc1 += bc[threadIdx.x + 256];
        acc2 += bc[threadIdx.x + 512];
    }
    __shared__ float sums[768];
    sums[threadIdx.x]       = acc0;
    sums[threadIdx.x + 256] = acc1;
    sums[threadIdx.x + 512] = acc2;
    __syncthreads();

    // one column per thread; stride-3 -> max 2 lanes/bank, free on CDNA4.
    const float sxx = sums[3 * threadIdx.x + 0];
    const float srr = sums[3 * threadIdx.x + 1];
    const float sxr = sums[3 * threadIdx.x + 2];
    float term = sxr / (fmaxf(sqrtf(sxx), EPS_F) * fmaxf(sqrtf(srr), EPS_F));
    if (half == 0 && threadIdx.x < CHUNKS)
        term += rowpart[p * CHUNKS + threadIdx.x];

    #pragma unroll
    for (int m = 32; m > 0; m >>= 1) term += __shfl_down(term, m, 64);
    __shared__ float ws4[4];
    if ((threadIdx.x & 63) == 0) ws4[threadIdx.x >> 6] = term;
    __syncthreads();

    __shared__ bool last;
    if (threadIdx.x == 0) {
        const float total = ws4[0] + ws4[1] + ws4[2] + ws4[3];
        __hip_atomic_store(&planepart[blockIdx.x], total, __ATOMIC_RELEASE,
                           __HIP_MEMORY_SCOPE_AGENT);
        const unsigned int prev = __hip_atomic_fetch_add(
            counter, 1u, __ATOMIC_ACQ_REL, __HIP_MEMORY_SCOPE_AGENT);
        last = (prev == K2_BLOCKS - 1);
    }
    __syncthreads();

    if (last && threadIdx.x < 64) {
        const int t = threadIdx.x;
        float v = __hip_atomic_load(&planepart[t], __ATOMIC_ACQUIRE,
                                    __HIP_MEMORY_SCOPE_AGENT);
        if (t < K2_BLOCKS - 64)
            v += __hip_atomic_load(&planepart[t + 64], __ATOMIC_ACQUIRE,
                                   __HIP_MEMORY_SCOPE_AGENT);
        #pragma unroll
        for (int m = 32; m > 0; m >>= 1) v += __shfl_down(v, m, 64);
        if (t == 0) out[0] = SCALE * v;
    }
}

extern "C" void kernel_launch(void* const* d_in, const int* in_sizes, int n_in,
                              void* d_out, int out_size, void* d_ws, size_t ws_size,
                              hipStream_t stream) {
    const float* x   = (const float*)d_in[0];
    const float* ref = (const float*)d_in[1];
    float* out = (float*)d_out;

    float* colpart   = (float*)d_ws;                      // 768*1536 floats
    float* rowpart   = colpart + (size_t)NBLK * STATS3;   // 768 floats
    float* planepart = rowpart + NBLK;                    // 96 floats
    unsigned int* counter = (unsigned int*)(planepart + K2_BLOCKS);  // 1 uint

    spl_main_kernel<<<NBLK, 256, 0, stream>>>(x, ref, colpart, rowpart, counter);
    spl_reduce_kernel<<<K2_BLOCKS, 256, 0, stream>>>(colpart, rowpart, planepart,
                                                     counter, out);
}